// Round 13
// baseline (378.963 us; speedup 1.0000x reference)
//
#include <hip/hip_runtime.h>
#include <math.h>

#define MCENT 16
#define KNN   64
#define NBINS 512
#define RBINS 256
#define CAP   7936
#define SKEYS 1024
#define FPSB  512
#define FPST  256
#define NPT   16
#define MLPT  1024

__device__ __forceinline__ float gelu_f(float x){
    return 0.5f * x * (1.0f + erff(x * 0.70710678118654752440f));
}

// Contiguous 1/8 slice of [0,NP) per XCD (blockIdx%8 heuristic; wrong mapping
// costs only locality, never correctness).
__device__ __forceinline__ void xcd_slice(int NP, int B, int bid, int tpb, int tid,
                                          int* q0, int* s1, int* step){
    int xcd = bid & 7, j = bid >> 3, Bx = B >> 3;
    long long np = NP;
    *q0   = (int)((np * xcd) >> 3) + j*tpb + tid;
    *s1   = (int)((np * (xcd+1)) >> 3);
    *step = Bx * tpb;
}

// Zeroes ghist/cnt/partials BEFORE the cooperative kernel (stream order
// guarantees completion) — removes the poll-ordering hazard.
__global__ void init_kernel(unsigned int* __restrict__ ghist,
                            unsigned int* __restrict__ cnt,
                            unsigned long long* __restrict__ partials){
    const int T = gridDim.x * blockDim.x;
    int t = blockIdx.x * blockDim.x + threadIdx.x;
    for (int i = t; i < MCENT*NBINS; i += T) ghist[i] = 0u;
    for (int i = t; i < (MCENT-1)*FPSB; i += T) partials[i] = 0ULL;
    if (t < MCENT) cnt[t] = 0u;
}

// ---------------- FPS: cooperative, register-resident, flag-poll sync ----------------
// Co-residency guaranteed by hipLaunchCooperativeKernel (proven working in
// round 1). Every block publishes a provably-nonzero key (low word =
// 0xFFFFFFFF-idx > 0), so polls terminate.
__global__ __launch_bounds__(FPST, 2) void fps_coop(
    const float* __restrict__ P, int N,
    unsigned long long* __restrict__ partials,   // [(MCENT-1)][FPSB], pre-zeroed
    float* __restrict__ cxy,
    float* __restrict__ outC)
{
    const int T = FPSB * FPST;
    const int t = blockIdx.x * FPST + threadIdx.x;
    const int lane = threadIdx.x & 63;
    const int wid  = threadIdx.x >> 6;

    float px[NPT], py[NPT], md[NPT];
#pragma unroll
    for (int i = 0; i < NPT; ++i){
        int g = t + i * T;
        if (g < N){
            float2 p = ((const float2*)P)[g];
            px[i] = p.x; py[i] = p.y; md[i] = 3.402823466e+38f;
        } else { px[i] = 0.f; py[i] = 0.f; md[i] = -1.0f; }   // invalid sentinel
    }

    __shared__ unsigned long long wred[FPST/64];
    int cur = 0;

    for (int k = 0; k < MCENT; ++k){
        if (blockIdx.x == 0 && threadIdx.x == 0){
            float cx = P[2*cur], cy = P[2*cur+1];
            cxy[2*k] = cx; cxy[2*k+1] = cy;
            outC[2*k] = cx; outC[2*k+1] = cy;
        }
        if (k == MCENT-1) break;

        const float cx = P[2*cur], cy = P[2*cur+1];
        unsigned long long bk = 0ULL;
#pragma unroll
        for (int i = 0; i < NPT; ++i){
            // match np: (dx*dx) + (dy*dy), no fma contraction; min exact
            float dx = __fsub_rn(px[i], cx);
            float dy = __fsub_rn(py[i], cy);
            float d  = __fadd_rn(__fmul_rn(dx,dx), __fmul_rn(dy,dy));
            if (md[i] >= 0.0f){
                float nm = fminf(md[i], d);
                md[i] = nm;
                // max over min_d, tie -> lowest index (np argmax picks first)
                unsigned long long key =
                    ((unsigned long long)__float_as_uint(nm) << 32)
                    | (unsigned long long)(0xFFFFFFFFu - (unsigned)(t + i*T));
                if (key > bk) bk = key;
            }
        }
#pragma unroll
        for (int off = 32; off > 0; off >>= 1){
            unsigned long long o = __shfl_xor(bk, off, 64);
            if (o > bk) bk = o;
        }
        if (lane == 0) wred[wid] = bk;
        __syncthreads();
        if (threadIdx.x == 0){
            unsigned long long b = wred[0];
#pragma unroll
            for (int w = 1; w < FPST/64; ++w) if (wred[w] > b) b = wred[w];
            __hip_atomic_store(&partials[k*FPSB + blockIdx.x], b,
                               __ATOMIC_RELEASE, __HIP_MEMORY_SCOPE_AGENT);
        }
        __syncthreads();    // publish-read of wred done before poll overwrites

        // poll all blocks' slots (2 per thread), then max-reduce
        unsigned long long pb = 0ULL;
        for (int i = threadIdx.x; i < FPSB; i += FPST){
            const unsigned long long* slot = &partials[k*FPSB + i];
            unsigned long long v = __hip_atomic_load(slot, __ATOMIC_RELAXED,
                                                     __HIP_MEMORY_SCOPE_AGENT);
            while (v == 0ULL){
                __builtin_amdgcn_s_sleep(1);
                v = __hip_atomic_load(slot, __ATOMIC_RELAXED,
                                      __HIP_MEMORY_SCOPE_AGENT);
            }
            if (v > pb) pb = v;
        }
#pragma unroll
        for (int off = 32; off > 0; off >>= 1){
            unsigned long long o = __shfl_xor(pb, off, 64);
            if (o > pb) pb = o;
        }
        if (lane == 0) wred[wid] = pb;
        __syncthreads();
        unsigned long long fin = wred[0];
#pragma unroll
        for (int w = 1; w < FPST/64; ++w) if (wred[w] > fin) fin = wred[w];
        __syncthreads();
        cur = (int)(0xFFFFFFFFu - (unsigned)(fin & 0xFFFFFFFFu));
    }
}

// ---------------- kNN pass 1: sampled exponent histogram (1/16) ----------------
__global__ __launch_bounds__(256) void hist_kernel(
    const float* __restrict__ P, int N,
    const float* __restrict__ cxy,
    unsigned int* __restrict__ ghist,
    unsigned int* __restrict__ rhist)
{
    __shared__ unsigned int h[MCENT*NBINS];
    __shared__ float scx[MCENT], scy[MCENT], scs2[MCENT];
    {
        int gi = blockIdx.x*blockDim.x + threadIdx.x;
        if (gi < MCENT*RBINS) rhist[gi] = 0u;
    }
    for (int i = threadIdx.x; i < MCENT*NBINS; i += blockDim.x) h[i] = 0u;
    if (threadIdx.x < MCENT){
        float a = cxy[2*threadIdx.x], b = cxy[2*threadIdx.x+1];
        scx[threadIdx.x] = a; scy[threadIdx.x] = b;
        scs2[threadIdx.x] = __fadd_rn(__fmul_rn(a,a), __fmul_rn(b,b));
    }
    __syncthreads();
    const int T    = gridDim.x * blockDim.x;
    const int NP16 = (N >> 1) >> 4;     // every 16th float4-pair
    for (int q = blockIdx.x*blockDim.x + threadIdx.x; q < NP16; q += T){
        float4 p = ((const float4*)P)[(size_t)q << 4];
        float ps20 = __fadd_rn(__fmul_rn(p.x,p.x), __fmul_rn(p.y,p.y));
        float ps21 = __fadd_rn(__fmul_rn(p.z,p.z), __fmul_rn(p.w,p.w));
#pragma unroll
        for (int m = 0; m < MCENT; ++m){
            // match reference expanded form: ps2 - 2*dot + cs2
            float dot0 = __fadd_rn(__fmul_rn(scx[m],p.x), __fmul_rn(scy[m],p.y));
            float d20  = __fadd_rn(__fsub_rn(ps20, __fmul_rn(2.0f,dot0)), scs2[m]);
            atomicAdd(&h[m*NBINS + (__float_as_uint(fmaxf(d20,0.0f)) >> 22)], 1u);
            float dot1 = __fadd_rn(__fmul_rn(scx[m],p.z), __fmul_rn(scy[m],p.w));
            float d21  = __fadd_rn(__fsub_rn(ps21, __fmul_rn(2.0f,dot1)), scs2[m]);
            atomicAdd(&h[m*NBINS + (__float_as_uint(fmaxf(d21,0.0f)) >> 22)], 1u);
        }
    }
    __syncthreads();
    for (int i = threadIdx.x; i < MCENT*NBINS; i += blockDim.x){
        unsigned v = h[i];
        if (v) atomicAdd(&ghist[i], v);
    }
}

// Coarse threshold -> sc2 (single source; refine & collect use identical bits).
__global__ void thr_kernel(const unsigned int* __restrict__ ghist,
                           float* __restrict__ sc2){
    int m = threadIdx.x;
    if (m < MCENT){
        unsigned cum = 0; int B = NBINS-1;
        for (int b = 0; b < NBINS; ++b){
            cum += ghist[m*NBINS + b];
            if (cum >= KNN){ B = b; break; }
        }
        sc2[m] = 255.0f / __uint_as_float((unsigned)(B+1) << 22);
    }
}

// ---------------- refine: full-N linear histogram within [0, thrc) ----------------
__global__ __launch_bounds__(256) void refine_kernel(
    const float* __restrict__ P, int N,
    const float* __restrict__ cxy,
    const float* __restrict__ sc2,
    unsigned int* __restrict__ rhist)
{
    __shared__ unsigned int h[MCENT*RBINS];    // 16 KB
    __shared__ float scx[MCENT], scy[MCENT], scs2[MCENT], ssc[MCENT];
    for (int i = threadIdx.x; i < MCENT*RBINS; i += 256) h[i] = 0u;
    if (threadIdx.x < MCENT){
        float a = cxy[2*threadIdx.x], b = cxy[2*threadIdx.x+1];
        scx[threadIdx.x]=a; scy[threadIdx.x]=b;
        scs2[threadIdx.x]=__fadd_rn(__fmul_rn(a,a),__fmul_rn(b,b));
        ssc[threadIdx.x]=sc2[threadIdx.x];
    }
    __syncthreads();
    const int NP = N >> 1;
    int q0, s1, st;
    xcd_slice(NP, gridDim.x, blockIdx.x, 256, threadIdx.x, &q0, &s1, &st);
    for (int q = q0; q < s1; q += st){
        float4 p = ((const float4*)P)[q];
        float ps20 = __fadd_rn(__fmul_rn(p.x,p.x), __fmul_rn(p.y,p.y));
        float ps21 = __fadd_rn(__fmul_rn(p.z,p.z), __fmul_rn(p.w,p.w));
#pragma unroll
        for (int m = 0; m < MCENT; ++m){
            float dot0 = __fadd_rn(__fmul_rn(scx[m],p.x), __fmul_rn(scy[m],p.y));
            float d20  = __fadd_rn(__fsub_rn(ps20, __fmul_rn(2.0f,dot0)), scs2[m]);
            int b0 = (int)(fmaxf(d20, 0.0f) * ssc[m]);
            if (b0 < RBINS) atomicAdd(&h[m*RBINS + b0], 1u);
            float dot1 = __fadd_rn(__fmul_rn(scx[m],p.z), __fmul_rn(scy[m],p.w));
            float d21  = __fadd_rn(__fsub_rn(ps21, __fmul_rn(2.0f,dot1)), scs2[m]);
            int b1 = (int)(fmaxf(d21, 0.0f) * ssc[m]);
            if (b1 < RBINS) atomicAdd(&h[m*RBINS + b1], 1u);
        }
    }
    if ((N & 1) && blockIdx.x == 0 && threadIdx.x == 0){
        int g = N-1;
        float x = P[2*g], y = P[2*g+1];
        float ps2 = __fadd_rn(__fmul_rn(x,x), __fmul_rn(y,y));
        for (int m = 0; m < MCENT; ++m){
            float dot = __fadd_rn(__fmul_rn(scx[m],x), __fmul_rn(scy[m],y));
            float d2  = __fadd_rn(__fsub_rn(ps2, __fmul_rn(2.0f,dot)), scs2[m]);
            int b = (int)(fmaxf(d2, 0.0f) * ssc[m]);
            if (b < RBINS) atomicAdd(&h[m*RBINS + b], 1u);
        }
    }
    __syncthreads();
    for (int i = threadIdx.x; i < MCENT*RBINS; i += blockDim.x){
        unsigned v = h[i];
        if (v) atomicAdd(&rhist[i], v);
    }
}

// Tight bin bound from rhist.
__global__ void thr2_kernel(const unsigned int* __restrict__ rhist,
                            int* __restrict__ B2){
    int m = threadIdx.x;
    if (m < MCENT){
        unsigned cum = 0; int B = RBINS-1;
        for (int b = 0; b < RBINS; ++b){
            cum += rhist[m*RBINS + b];
            if (cum >= KNN){ B = b; break; }
        }
        B2[m] = B;
    }
}

// ---------------- collect: bin(d2) <= B2 (~70-150 candidates/center) ----------------
__global__ __launch_bounds__(256) void collect_kernel(
    const float* __restrict__ P, int N,
    const float* __restrict__ cxy,
    const float* __restrict__ sc2,
    const int* __restrict__ B2,
    unsigned int* __restrict__ cnt,
    float* __restrict__ cd2,
    int* __restrict__ cidx)
{
    __shared__ float scx[MCENT], scy[MCENT], scs2[MCENT], ssc[MCENT];
    __shared__ int sB2[MCENT];
    if (threadIdx.x < MCENT){
        float a = cxy[2*threadIdx.x], b = cxy[2*threadIdx.x+1];
        scx[threadIdx.x]=a; scy[threadIdx.x]=b;
        scs2[threadIdx.x]=__fadd_rn(__fmul_rn(a,a),__fmul_rn(b,b));
        ssc[threadIdx.x]=sc2[threadIdx.x];
        sB2[threadIdx.x]=B2[threadIdx.x];
    }
    __syncthreads();
    const int NP = N >> 1;
    int q0, s1, st;
    xcd_slice(NP, gridDim.x, blockIdx.x, 256, threadIdx.x, &q0, &s1, &st);
    for (int q = q0; q < s1; q += st){
        float4 p = ((const float4*)P)[q];
        float ps20 = __fadd_rn(__fmul_rn(p.x,p.x), __fmul_rn(p.y,p.y));
        float ps21 = __fadd_rn(__fmul_rn(p.z,p.z), __fmul_rn(p.w,p.w));
        int g = 2*q;
#pragma unroll
        for (int m = 0; m < MCENT; ++m){
            float dot0 = __fadd_rn(__fmul_rn(scx[m],p.x), __fmul_rn(scy[m],p.y));
            float d20  = __fadd_rn(__fsub_rn(ps20, __fmul_rn(2.0f,dot0)), scs2[m]);
            if ((int)(fmaxf(d20,0.0f) * ssc[m]) <= sB2[m]){
                unsigned pos = atomicAdd(&cnt[m], 1u);
                if (pos < CAP){ cd2[m*CAP+pos]=d20; cidx[m*CAP+pos]=g; }
            }
            float dot1 = __fadd_rn(__fmul_rn(scx[m],p.z), __fmul_rn(scy[m],p.w));
            float d21  = __fadd_rn(__fsub_rn(ps21, __fmul_rn(2.0f,dot1)), scs2[m]);
            if ((int)(fmaxf(d21,0.0f) * ssc[m]) <= sB2[m]){
                unsigned pos = atomicAdd(&cnt[m], 1u);
                if (pos < CAP){ cd2[m*CAP+pos]=d21; cidx[m*CAP+pos]=g+1; }
            }
        }
    }
    if ((N & 1) && blockIdx.x == 0 && threadIdx.x == 0){
        int g = N-1;
        float x = P[2*g], y = P[2*g+1];
        float ps2 = __fadd_rn(__fmul_rn(x,x), __fmul_rn(y,y));
        for (int m = 0; m < MCENT; ++m){
            float dot = __fadd_rn(__fmul_rn(scx[m],x), __fmul_rn(scy[m],y));
            float d2  = __fadd_rn(__fsub_rn(ps2, __fmul_rn(2.0f,dot)), scs2[m]);
            if ((int)(fmaxf(d2,0.0f) * ssc[m]) <= sB2[m]){
                unsigned pos = atomicAdd(&cnt[m], 1u);
                if (pos < CAP){ cd2[m*CAP+pos]=d2; cidx[m*CAP+pos]=g; }
            }
        }
    }
}

// ---------------- fused select + features + MLP: 1024 threads/center ----------------
__global__ __launch_bounds__(MLPT) void mlp_kernel(
    const float* __restrict__ P,
    const float* __restrict__ cxy,
    const unsigned int* __restrict__ cnt,
    const float* __restrict__ cd2,
    const int* __restrict__ cidx,
    const float* __restrict__ W1, const float* __restrict__ b1,
    const float* __restrict__ W2, const float* __restrict__ b2,
    const float* __restrict__ W3, const float* __restrict__ b3,
    const float* __restrict__ W4, const float* __restrict__ b4,
    float* __restrict__ outF)
{
    const int m = blockIdx.x;
    const int tid = threadIdx.x;
    __shared__ float feat[KNN][32];
    __shared__ float h1s[KNN][64];
    __shared__ float sW1[29*64];
    __shared__ float sW2[64*128];
    __shared__ float pmax[8][128], psum[8][128];
    __shared__ float z[260];
    __shared__ float part[8][128];
    __shared__ float zz[128];
    __shared__ unsigned long long kkeys[SKEYS];
    __shared__ int snbr[KNN];

    {
        const float4* s2 = (const float4*)W2;
        float4* d2 = (float4*)sW2;
        d2[tid]        = s2[tid];
        d2[tid + 1024] = s2[tid + 1024];
        if (tid < 464) ((float4*)sW1)[tid] = ((const float4*)W1)[tid];
    }

    // ---- selection: exact rank over candidates (keys unique: idx in low bits) ----
    unsigned c = cnt[m]; if (c > CAP) c = CAP;
    if (c <= SKEYS){
        if (tid < (int)c){
            unsigned u = __float_as_uint(cd2[m*CAP+tid]);
            u = (u & 0x80000000u) ? ~u : (u | 0x80000000u);  // float -> sortable
            kkeys[tid] = ((unsigned long long)u << 32)
                       | (unsigned long long)(unsigned)cidx[m*CAP+tid];
        }
        __syncthreads();
        if (tid < (int)c){
            unsigned long long ki = kkeys[tid];
            int rank = 0;
            for (int j = 0; j < (int)c; ++j) rank += (kkeys[j] < ki);
            if (rank < KNN) snbr[rank] = (int)(unsigned)(ki & 0xFFFFFFFFu);
        }
    } else {
        for (int i = tid; i < (int)c; i += MLPT){
            unsigned ui = __float_as_uint(cd2[m*CAP+i]);
            ui = (ui & 0x80000000u) ? ~ui : (ui | 0x80000000u);
            unsigned long long ki = ((unsigned long long)ui << 32)
                                  | (unsigned long long)(unsigned)cidx[m*CAP+i];
            int rank = 0;
            for (int j = 0; j < (int)c; ++j){
                unsigned uj = __float_as_uint(cd2[m*CAP+j]);
                uj = (uj & 0x80000000u) ? ~uj : (uj | 0x80000000u);
                unsigned long long kj = ((unsigned long long)uj << 32)
                                      | (unsigned long long)(unsigned)cidx[m*CAP+j];
                rank += (kj < ki);
            }
            if (rank < KNN) snbr[rank] = (int)(unsigned)(ki & 0xFFFFFFFFu);
        }
    }
    __syncthreads();

    const float cx = cxy[2*m], cy = cxy[2*m+1];
    if (tid < KNN){
        int g = snbr[tid];
        float dx = P[2*g]   - cx;
        float dy = P[2*g+1] - cy;
        float r  = sqrtf(dx*dx + dy*dy);
        float th = atan2f(dy, dx);
        feat[tid][0]=dx; feat[tid][1]=dy; feat[tid][2]=r;
        feat[tid][3]=sinf(th); feat[tid][4]=cosf(th);
        float fx = dx, fy = dy;      // freqs 1,2,4,8,16,32
#pragma unroll
        for (int l = 0; l < 6; ++l){
            feat[tid][5+4*l+0]=sinf(fx);
            feat[tid][5+4*l+1]=sinf(fy);
            feat[tid][5+4*l+2]=cosf(fx);
            feat[tid][5+4*l+3]=cosf(fy);
            fx += fx; fy += fy;
        }
    }
    __syncthreads();

#pragma unroll
    for (int rep = 0; rep < 4; ++rep){
        int o = rep*MLPT + tid;
        int k = o >> 6, j = o & 63;
        float acc = b1[j];
#pragma unroll
        for (int cc = 0; cc < 29; ++cc) acc += feat[k][cc] * sW1[cc*64 + j];
        h1s[k][j] = gelu_f(acc);
    }
    __syncthreads();

    {
        int j = tid & 127, kh = tid >> 7;
        float lmax = -3.402823466e+38f, lsum = 0.f;
        for (int kk = 0; kk < 8; ++kk){
            int k = kh*8 + kk;
            float acc = b2[j];
#pragma unroll 8
            for (int i = 0; i < 64; ++i) acc += h1s[k][i] * sW2[i*128 + j];
            float v = gelu_f(acc);
            lmax = fmaxf(lmax, v);
            lsum += v;
        }
        pmax[kh][j] = lmax; psum[kh][j] = lsum;
    }
    __syncthreads();
    if (tid < 128){
        float mx = pmax[0][tid], sm = psum[0][tid];
#pragma unroll
        for (int w = 1; w < 8; ++w){ mx = fmaxf(mx, pmax[w][tid]); sm += psum[w][tid]; }
        z[tid]       = mx;
        z[128 + tid] = sm * (1.0f/64.0f);
    }
    if (tid >= 128 && tid < 192){   // r stats on wave 2
        int l = tid - 128;
        float r = feat[l][2];
        float s = r, mx = r, mn = r;
        for (int off = 1; off < 64; off <<= 1){
            s  += __shfl_xor(s, off, 64);
            mx  = fmaxf(mx, __shfl_xor(mx, off, 64));
            mn  = fminf(mn, __shfl_xor(mn, off, 64));
        }
        float mean = s * (1.0f/64.0f);
        float dv = (r-mean)*(r-mean);
        for (int off = 1; off < 64; off <<= 1) dv += __shfl_xor(dv, off, 64);
        if (l == 0){
            z[256]=mean; z[257]=mx; z[258]=mn; z[259]=sqrtf(dv*(1.0f/63.0f));
        }
    }
    __syncthreads();

    {
        int j = tid & 127, seg = tid >> 7;
        int i0  = (seg < 4) ? seg*33 : 132 + (seg-4)*32;
        int cntn = (seg < 4) ? 33 : 32;
        float acc = 0.f;
        for (int i = i0; i < i0 + cntn; ++i) acc += z[i]*W3[i*128+j];
        part[seg][j] = acc;
    }
    __syncthreads();
    if (tid < 128){
        float a = part[0][tid];
#pragma unroll
        for (int w = 1; w < 8; ++w) a += part[w][tid];
        zz[tid] = gelu_f(a + b3[tid]);
    }
    __syncthreads();
    {
        int j = tid & 127, seg = tid >> 7;
        float acc = 0.f;
#pragma unroll
        for (int i = seg*16; i < seg*16+16; ++i) acc += zz[i]*W4[i*128+j];
        part[seg][j] = acc;
    }
    __syncthreads();
    if (tid < 128){
        float a = part[0][tid];
#pragma unroll
        for (int w = 1; w < 8; ++w) a += part[w][tid];
        outF[m*128 + tid] = a + b4[tid];
    }
}

extern "C" void kernel_launch(void* const* d_in, const int* in_sizes, int n_in,
                              void* d_out, int out_size, void* d_ws, size_t ws_size,
                              hipStream_t stream)
{
    const float* P  = (const float*)d_in[0];
    const float* W1 = (const float*)d_in[1];
    const float* b1 = (const float*)d_in[2];
    const float* W2 = (const float*)d_in[3];
    const float* b2 = (const float*)d_in[4];
    const float* W3 = (const float*)d_in[5];
    const float* b3 = (const float*)d_in[6];
    const float* W4 = (const float*)d_in[7];
    const float* b4 = (const float*)d_in[8];
    int N = in_sizes[0] / 2;
    float* outF = (float*)d_out;               // [16][128]
    float* outC = outF + MCENT*128;            // [16][2]
    (void)n_in; (void)out_size; (void)ws_size;

    char* base = (char*)d_ws;
    size_t off = 0;
    auto take = [&](size_t bytes)->char*{
        char* p = base + off;
        off = (off + bytes + 255) & ~(size_t)255;
        return p;
    };
    unsigned long long* partials = (unsigned long long*)take((size_t)(MCENT-1)*FPSB*8);
    float* cxy         = (float*)take(MCENT*2*4);
    unsigned int* ghist= (unsigned int*)take(MCENT*NBINS*4);
    unsigned int* rhist= (unsigned int*)take(MCENT*RBINS*4);
    unsigned int* cnt  = (unsigned int*)take(MCENT*4);
    float* sc2         = (float*)take(MCENT*4);
    int*   B2          = (int*)  take(MCENT*4);
    float* cd2         = (float*)take((size_t)MCENT*CAP*4);
    int*   cidx        = (int*)  take((size_t)MCENT*CAP*4);

    init_kernel<<<32, 256, 0, stream>>>(ghist, cnt, partials);

    void* fargs[] = { (void*)&P, (void*)&N, (void*)&partials,
                      (void*)&cxy, (void*)&outC };
    hipLaunchCooperativeKernel((const void*)fps_coop, dim3(FPSB), dim3(FPST),
                               fargs, 0, stream);

    hist_kernel<<<128, 256, 0, stream>>>(P, N, cxy, ghist, rhist);
    thr_kernel<<<1, 64, 0, stream>>>(ghist, sc2);
    refine_kernel<<<1024, 256, 0, stream>>>(P, N, cxy, sc2, rhist);
    thr2_kernel<<<1, 64, 0, stream>>>(rhist, B2);
    collect_kernel<<<1024, 256, 0, stream>>>(P, N, cxy, sc2, B2, cnt, cd2, cidx);
    mlp_kernel<<<MCENT, MLPT, 0, stream>>>(P, cxy, cnt, cd2, cidx,
                                           W1,b1,W2,b2,W3,b3,W4,b4, outF);
}

// Round 14
// 341.240 us; speedup vs baseline: 1.1105x; 1.1105x over previous
//
#include <hip/hip_runtime.h>
#include <math.h>

#define MCENT 16
#define KNN   64
#define NBINS 512
#define RBINS 256
#define CAP   7936
#define SKEYS 1024
#define FPSB  512
#define FPST  256
#define NPT   16
#define MLPT  1024

__device__ __forceinline__ float gelu_f(float x){
    return 0.5f * x * (1.0f + erff(x * 0.70710678118654752440f));
}

// Contiguous 1/8 slice of [0,NP) per XCD (blockIdx%8 heuristic; wrong mapping
// costs only locality, never correctness).
__device__ __forceinline__ void xcd_slice(int NP, int B, int bid, int tpb, int tid,
                                          int* q0, int* s1, int* step){
    int xcd = bid & 7, j = bid >> 3, Bx = B >> 3;
    long long np = NP;
    *q0   = (int)((np * xcd) >> 3) + j*tpb + tid;
    *s1   = (int)((np * (xcd+1)) >> 3);
    *step = Bx * tpb;
}

// Zeroes ghist/cnt/partials/bcast BEFORE the cooperative kernel (stream order
// guarantees completion) — removes the poll-ordering hazard.
__global__ void init_kernel(unsigned int* __restrict__ ghist,
                            unsigned int* __restrict__ cnt,
                            unsigned long long* __restrict__ partials,
                            unsigned int* __restrict__ bcast){
    const int T = gridDim.x * blockDim.x;
    int t = blockIdx.x * blockDim.x + threadIdx.x;
    for (int i = t; i < MCENT*NBINS; i += T) ghist[i] = 0u;
    for (int i = t; i < (MCENT-1)*FPSB; i += T) partials[i] = 0ULL;
    if (t < MCENT) cnt[t] = 0u;
    if (t < MCENT) bcast[t] = 0u;
}

// ---------------- FPS: cooperative, register-resident, two-level flag sync ----------------
// Pollers cut from 131072 threads (round-13: 10us/iter contention) to 512+256:
// block 0 gathers the 512 partials; all other blocks spin one thread on bcast[k].
// Every published value is provably nonzero; all flags pre-zeroed; one row per
// iteration -> no ABA; co-residency via hipLaunchCooperativeKernel.
__global__ __launch_bounds__(FPST, 2) void fps_coop(
    const float* __restrict__ P, int N,
    unsigned long long* __restrict__ partials,   // [(MCENT-1)][FPSB], pre-zeroed
    unsigned int* __restrict__ bcast,            // [MCENT], pre-zeroed
    float* __restrict__ cxy,
    float* __restrict__ outC)
{
    const int T = FPSB * FPST;
    const int t = blockIdx.x * FPST + threadIdx.x;
    const int lane = threadIdx.x & 63;
    const int wid  = threadIdx.x >> 6;

    float px[NPT], py[NPT], md[NPT];
#pragma unroll
    for (int i = 0; i < NPT; ++i){
        int g = t + i * T;
        if (g < N){
            float2 p = ((const float2*)P)[g];
            px[i] = p.x; py[i] = p.y; md[i] = 3.402823466e+38f;
        } else { px[i] = 0.f; py[i] = 0.f; md[i] = -1.0f; }   // invalid sentinel
    }

    __shared__ unsigned long long wred[FPST/64];
    __shared__ int s_cur;
    int cur = 0;

    for (int k = 0; k < MCENT; ++k){
        if (blockIdx.x == 0 && threadIdx.x == 0){
            float cx = P[2*cur], cy = P[2*cur+1];
            cxy[2*k] = cx; cxy[2*k+1] = cy;
            outC[2*k] = cx; outC[2*k+1] = cy;
        }
        if (k == MCENT-1) break;

        const float cx = P[2*cur], cy = P[2*cur+1];
        unsigned long long bk = 0ULL;
#pragma unroll
        for (int i = 0; i < NPT; ++i){
            // match np: (dx*dx) + (dy*dy), no fma contraction; min exact
            float dx = __fsub_rn(px[i], cx);
            float dy = __fsub_rn(py[i], cy);
            float d  = __fadd_rn(__fmul_rn(dx,dx), __fmul_rn(dy,dy));
            if (md[i] >= 0.0f){
                float nm = fminf(md[i], d);
                md[i] = nm;
                // max over min_d, tie -> lowest index (np argmax picks first)
                unsigned long long key =
                    ((unsigned long long)__float_as_uint(nm) << 32)
                    | (unsigned long long)(0xFFFFFFFFu - (unsigned)(t + i*T));
                if (key > bk) bk = key;
            }
        }
#pragma unroll
        for (int off = 32; off > 0; off >>= 1){
            unsigned long long o = __shfl_xor(bk, off, 64);
            if (o > bk) bk = o;
        }
        if (lane == 0) wred[wid] = bk;
        __syncthreads();
        if (threadIdx.x == 0){
            unsigned long long b = wred[0];
#pragma unroll
            for (int w = 1; w < FPST/64; ++w) if (wred[w] > b) b = wred[w];
            __hip_atomic_store(&partials[k*FPSB + blockIdx.x], b,
                               __ATOMIC_RELEASE, __HIP_MEMORY_SCOPE_AGENT);
        }
        __syncthreads();    // wred free for reuse below

        if (blockIdx.x == 0){
            // gather all 512 partials (2 slots/thread), reduce, broadcast
            unsigned long long pb = 0ULL;
            for (int i = threadIdx.x; i < FPSB; i += FPST){
                const unsigned long long* slot = &partials[k*FPSB + i];
                unsigned long long v = __hip_atomic_load(slot, __ATOMIC_RELAXED,
                                                         __HIP_MEMORY_SCOPE_AGENT);
                while (v == 0ULL){
                    __builtin_amdgcn_s_sleep(2);
                    v = __hip_atomic_load(slot, __ATOMIC_RELAXED,
                                          __HIP_MEMORY_SCOPE_AGENT);
                }
                if (v > pb) pb = v;
            }
#pragma unroll
            for (int off = 32; off > 0; off >>= 1){
                unsigned long long o = __shfl_xor(pb, off, 64);
                if (o > pb) pb = o;
            }
            if (lane == 0) wred[wid] = pb;
            __syncthreads();
            if (threadIdx.x == 0){
                unsigned long long fin = wred[0];
#pragma unroll
                for (int w = 1; w < FPST/64; ++w) if (wred[w] > fin) fin = wred[w];
                int c = (int)(0xFFFFFFFFu - (unsigned)(fin & 0xFFFFFFFFu));
                s_cur = c;
                __hip_atomic_store(&bcast[k], (unsigned)(c + 1),
                                   __ATOMIC_RELEASE, __HIP_MEMORY_SCOPE_AGENT);
            }
            __syncthreads();
        } else {
            // one thread spins on the broadcast word with backoff
            if (threadIdx.x == 0){
                unsigned v = __hip_atomic_load(&bcast[k], __ATOMIC_RELAXED,
                                               __HIP_MEMORY_SCOPE_AGENT);
                while (v == 0u){
                    __builtin_amdgcn_s_sleep(4);
                    v = __hip_atomic_load(&bcast[k], __ATOMIC_RELAXED,
                                          __HIP_MEMORY_SCOPE_AGENT);
                }
                s_cur = (int)v - 1;
            }
            __syncthreads();
        }
        cur = s_cur;
    }
}

// ---------------- kNN pass 1: sampled exponent histogram (1/16) ----------------
__global__ __launch_bounds__(256) void hist_kernel(
    const float* __restrict__ P, int N,
    const float* __restrict__ cxy,
    unsigned int* __restrict__ ghist,
    unsigned int* __restrict__ rhist)
{
    __shared__ unsigned int h[MCENT*NBINS];
    __shared__ float scx[MCENT], scy[MCENT], scs2[MCENT];
    {
        int gi = blockIdx.x*blockDim.x + threadIdx.x;
        if (gi < MCENT*RBINS) rhist[gi] = 0u;
    }
    for (int i = threadIdx.x; i < MCENT*NBINS; i += blockDim.x) h[i] = 0u;
    if (threadIdx.x < MCENT){
        float a = cxy[2*threadIdx.x], b = cxy[2*threadIdx.x+1];
        scx[threadIdx.x] = a; scy[threadIdx.x] = b;
        scs2[threadIdx.x] = __fadd_rn(__fmul_rn(a,a), __fmul_rn(b,b));
    }
    __syncthreads();
    const int T    = gridDim.x * blockDim.x;
    const int NP16 = (N >> 1) >> 4;     // every 16th float4-pair
    for (int q = blockIdx.x*blockDim.x + threadIdx.x; q < NP16; q += T){
        float4 p = ((const float4*)P)[(size_t)q << 4];
        float ps20 = __fadd_rn(__fmul_rn(p.x,p.x), __fmul_rn(p.y,p.y));
        float ps21 = __fadd_rn(__fmul_rn(p.z,p.z), __fmul_rn(p.w,p.w));
#pragma unroll
        for (int m = 0; m < MCENT; ++m){
            // match reference expanded form: ps2 - 2*dot + cs2
            float dot0 = __fadd_rn(__fmul_rn(scx[m],p.x), __fmul_rn(scy[m],p.y));
            float d20  = __fadd_rn(__fsub_rn(ps20, __fmul_rn(2.0f,dot0)), scs2[m]);
            atomicAdd(&h[m*NBINS + (__float_as_uint(fmaxf(d20,0.0f)) >> 22)], 1u);
            float dot1 = __fadd_rn(__fmul_rn(scx[m],p.z), __fmul_rn(scy[m],p.w));
            float d21  = __fadd_rn(__fsub_rn(ps21, __fmul_rn(2.0f,dot1)), scs2[m]);
            atomicAdd(&h[m*NBINS + (__float_as_uint(fmaxf(d21,0.0f)) >> 22)], 1u);
        }
    }
    __syncthreads();
    for (int i = threadIdx.x; i < MCENT*NBINS; i += blockDim.x){
        unsigned v = h[i];
        if (v) atomicAdd(&ghist[i], v);
    }
}

// Coarse threshold -> sc2 (single source; refine & collect use identical bits).
__global__ void thr_kernel(const unsigned int* __restrict__ ghist,
                           float* __restrict__ sc2){
    int m = threadIdx.x;
    if (m < MCENT){
        unsigned cum = 0; int B = NBINS-1;
        for (int b = 0; b < NBINS; ++b){
            cum += ghist[m*NBINS + b];
            if (cum >= KNN){ B = b; break; }
        }
        sc2[m] = 255.0f / __uint_as_float((unsigned)(B+1) << 22);
    }
}

// ---------------- refine: full-N linear histogram within [0, thrc) ----------------
__global__ __launch_bounds__(256) void refine_kernel(
    const float* __restrict__ P, int N,
    const float* __restrict__ cxy,
    const float* __restrict__ sc2,
    unsigned int* __restrict__ rhist)
{
    __shared__ unsigned int h[MCENT*RBINS];    // 16 KB
    __shared__ float scx[MCENT], scy[MCENT], scs2[MCENT], ssc[MCENT];
    for (int i = threadIdx.x; i < MCENT*RBINS; i += 256) h[i] = 0u;
    if (threadIdx.x < MCENT){
        float a = cxy[2*threadIdx.x], b = cxy[2*threadIdx.x+1];
        scx[threadIdx.x]=a; scy[threadIdx.x]=b;
        scs2[threadIdx.x]=__fadd_rn(__fmul_rn(a,a),__fmul_rn(b,b));
        ssc[threadIdx.x]=sc2[threadIdx.x];
    }
    __syncthreads();
    const int NP = N >> 1;
    int q0, s1, st;
    xcd_slice(NP, gridDim.x, blockIdx.x, 256, threadIdx.x, &q0, &s1, &st);
    for (int q = q0; q < s1; q += st){
        float4 p = ((const float4*)P)[q];
        float ps20 = __fadd_rn(__fmul_rn(p.x,p.x), __fmul_rn(p.y,p.y));
        float ps21 = __fadd_rn(__fmul_rn(p.z,p.z), __fmul_rn(p.w,p.w));
#pragma unroll
        for (int m = 0; m < MCENT; ++m){
            float dot0 = __fadd_rn(__fmul_rn(scx[m],p.x), __fmul_rn(scy[m],p.y));
            float d20  = __fadd_rn(__fsub_rn(ps20, __fmul_rn(2.0f,dot0)), scs2[m]);
            int b0 = (int)(fmaxf(d20, 0.0f) * ssc[m]);
            if (b0 < RBINS) atomicAdd(&h[m*RBINS + b0], 1u);
            float dot1 = __fadd_rn(__fmul_rn(scx[m],p.z), __fmul_rn(scy[m],p.w));
            float d21  = __fadd_rn(__fsub_rn(ps21, __fmul_rn(2.0f,dot1)), scs2[m]);
            int b1 = (int)(fmaxf(d21, 0.0f) * ssc[m]);
            if (b1 < RBINS) atomicAdd(&h[m*RBINS + b1], 1u);
        }
    }
    if ((N & 1) && blockIdx.x == 0 && threadIdx.x == 0){
        int g = N-1;
        float x = P[2*g], y = P[2*g+1];
        float ps2 = __fadd_rn(__fmul_rn(x,x), __fmul_rn(y,y));
        for (int m = 0; m < MCENT; ++m){
            float dot = __fadd_rn(__fmul_rn(scx[m],x), __fmul_rn(scy[m],y));
            float d2  = __fadd_rn(__fsub_rn(ps2, __fmul_rn(2.0f,dot)), scs2[m]);
            int b = (int)(fmaxf(d2, 0.0f) * ssc[m]);
            if (b < RBINS) atomicAdd(&h[m*RBINS + b], 1u);
        }
    }
    __syncthreads();
    for (int i = threadIdx.x; i < MCENT*RBINS; i += blockDim.x){
        unsigned v = h[i];
        if (v) atomicAdd(&rhist[i], v);
    }
}

// Tight bin bound from rhist.
__global__ void thr2_kernel(const unsigned int* __restrict__ rhist,
                            int* __restrict__ B2){
    int m = threadIdx.x;
    if (m < MCENT){
        unsigned cum = 0; int B = RBINS-1;
        for (int b = 0; b < RBINS; ++b){
            cum += rhist[m*RBINS + b];
            if (cum >= KNN){ B = b; break; }
        }
        B2[m] = B;
    }
}

// ---------------- collect: bin(d2) <= B2 (~70-150 candidates/center) ----------------
__global__ __launch_bounds__(256) void collect_kernel(
    const float* __restrict__ P, int N,
    const float* __restrict__ cxy,
    const float* __restrict__ sc2,
    const int* __restrict__ B2,
    unsigned int* __restrict__ cnt,
    float* __restrict__ cd2,
    int* __restrict__ cidx)
{
    __shared__ float scx[MCENT], scy[MCENT], scs2[MCENT], ssc[MCENT];
    __shared__ int sB2[MCENT];
    if (threadIdx.x < MCENT){
        float a = cxy[2*threadIdx.x], b = cxy[2*threadIdx.x+1];
        scx[threadIdx.x]=a; scy[threadIdx.x]=b;
        scs2[threadIdx.x]=__fadd_rn(__fmul_rn(a,a),__fmul_rn(b,b));
        ssc[threadIdx.x]=sc2[threadIdx.x];
        sB2[threadIdx.x]=B2[threadIdx.x];
    }
    __syncthreads();
    const int NP = N >> 1;
    int q0, s1, st;
    xcd_slice(NP, gridDim.x, blockIdx.x, 256, threadIdx.x, &q0, &s1, &st);
    for (int q = q0; q < s1; q += st){
        float4 p = ((const float4*)P)[q];
        float ps20 = __fadd_rn(__fmul_rn(p.x,p.x), __fmul_rn(p.y,p.y));
        float ps21 = __fadd_rn(__fmul_rn(p.z,p.z), __fmul_rn(p.w,p.w));
        int g = 2*q;
#pragma unroll
        for (int m = 0; m < MCENT; ++m){
            float dot0 = __fadd_rn(__fmul_rn(scx[m],p.x), __fmul_rn(scy[m],p.y));
            float d20  = __fadd_rn(__fsub_rn(ps20, __fmul_rn(2.0f,dot0)), scs2[m]);
            if ((int)(fmaxf(d20,0.0f) * ssc[m]) <= sB2[m]){
                unsigned pos = atomicAdd(&cnt[m], 1u);
                if (pos < CAP){ cd2[m*CAP+pos]=d20; cidx[m*CAP+pos]=g; }
            }
            float dot1 = __fadd_rn(__fmul_rn(scx[m],p.z), __fmul_rn(scy[m],p.w));
            float d21  = __fadd_rn(__fsub_rn(ps21, __fmul_rn(2.0f,dot1)), scs2[m]);
            if ((int)(fmaxf(d21,0.0f) * ssc[m]) <= sB2[m]){
                unsigned pos = atomicAdd(&cnt[m], 1u);
                if (pos < CAP){ cd2[m*CAP+pos]=d21; cidx[m*CAP+pos]=g+1; }
            }
        }
    }
    if ((N & 1) && blockIdx.x == 0 && threadIdx.x == 0){
        int g = N-1;
        float x = P[2*g], y = P[2*g+1];
        float ps2 = __fadd_rn(__fmul_rn(x,x), __fmul_rn(y,y));
        for (int m = 0; m < MCENT; ++m){
            float dot = __fadd_rn(__fmul_rn(scx[m],x), __fmul_rn(scy[m],y));
            float d2  = __fadd_rn(__fsub_rn(ps2, __fmul_rn(2.0f,dot)), scs2[m]);
            if ((int)(fmaxf(d2,0.0f) * ssc[m]) <= sB2[m]){
                unsigned pos = atomicAdd(&cnt[m], 1u);
                if (pos < CAP){ cd2[m*CAP+pos]=d2; cidx[m*CAP+pos]=g; }
            }
        }
    }
}

// ---------------- fused select + features + MLP: 1024 threads/center ----------------
__global__ __launch_bounds__(MLPT) void mlp_kernel(
    const float* __restrict__ P,
    const float* __restrict__ cxy,
    const unsigned int* __restrict__ cnt,
    const float* __restrict__ cd2,
    const int* __restrict__ cidx,
    const float* __restrict__ W1, const float* __restrict__ b1,
    const float* __restrict__ W2, const float* __restrict__ b2,
    const float* __restrict__ W3, const float* __restrict__ b3,
    const float* __restrict__ W4, const float* __restrict__ b4,
    float* __restrict__ outF)
{
    const int m = blockIdx.x;
    const int tid = threadIdx.x;
    __shared__ float feat[KNN][32];
    __shared__ float h1s[KNN][64];
    __shared__ float sW1[29*64];
    __shared__ float sW2[64*128];
    __shared__ float pmax[8][128], psum[8][128];
    __shared__ float z[260];
    __shared__ float part[8][128];
    __shared__ float zz[128];
    __shared__ unsigned long long kkeys[SKEYS];
    __shared__ int snbr[KNN];

    {
        const float4* s2 = (const float4*)W2;
        float4* d2 = (float4*)sW2;
        d2[tid]        = s2[tid];
        d2[tid + 1024] = s2[tid + 1024];
        if (tid < 464) ((float4*)sW1)[tid] = ((const float4*)W1)[tid];
    }

    // ---- selection: exact rank over candidates (keys unique: idx in low bits) ----
    unsigned c = cnt[m]; if (c > CAP) c = CAP;
    if (c <= SKEYS){
        if (tid < (int)c){
            unsigned u = __float_as_uint(cd2[m*CAP+tid]);
            u = (u & 0x80000000u) ? ~u : (u | 0x80000000u);  // float -> sortable
            kkeys[tid] = ((unsigned long long)u << 32)
                       | (unsigned long long)(unsigned)cidx[m*CAP+tid];
        }
        __syncthreads();
        if (tid < (int)c){
            unsigned long long ki = kkeys[tid];
            int rank = 0;
            for (int j = 0; j < (int)c; ++j) rank += (kkeys[j] < ki);
            if (rank < KNN) snbr[rank] = (int)(unsigned)(ki & 0xFFFFFFFFu);
        }
    } else {
        for (int i = tid; i < (int)c; i += MLPT){
            unsigned ui = __float_as_uint(cd2[m*CAP+i]);
            ui = (ui & 0x80000000u) ? ~ui : (ui | 0x80000000u);
            unsigned long long ki = ((unsigned long long)ui << 32)
                                  | (unsigned long long)(unsigned)cidx[m*CAP+i];
            int rank = 0;
            for (int j = 0; j < (int)c; ++j){
                unsigned uj = __float_as_uint(cd2[m*CAP+j]);
                uj = (uj & 0x80000000u) ? ~uj : (uj | 0x80000000u);
                unsigned long long kj = ((unsigned long long)uj << 32)
                                      | (unsigned long long)(unsigned)cidx[m*CAP+j];
                rank += (kj < ki);
            }
            if (rank < KNN) snbr[rank] = (int)(unsigned)(ki & 0xFFFFFFFFu);
        }
    }
    __syncthreads();

    const float cx = cxy[2*m], cy = cxy[2*m+1];
    if (tid < KNN){
        int g = snbr[tid];
        float dx = P[2*g]   - cx;
        float dy = P[2*g+1] - cy;
        float r  = sqrtf(dx*dx + dy*dy);
        float th = atan2f(dy, dx);
        feat[tid][0]=dx; feat[tid][1]=dy; feat[tid][2]=r;
        feat[tid][3]=sinf(th); feat[tid][4]=cosf(th);
        float fx = dx, fy = dy;      // freqs 1,2,4,8,16,32
#pragma unroll
        for (int l = 0; l < 6; ++l){
            feat[tid][5+4*l+0]=sinf(fx);
            feat[tid][5+4*l+1]=sinf(fy);
            feat[tid][5+4*l+2]=cosf(fx);
            feat[tid][5+4*l+3]=cosf(fy);
            fx += fx; fy += fy;
        }
    }
    __syncthreads();

#pragma unroll
    for (int rep = 0; rep < 4; ++rep){
        int o = rep*MLPT + tid;
        int k = o >> 6, j = o & 63;
        float acc = b1[j];
#pragma unroll
        for (int cc = 0; cc < 29; ++cc) acc += feat[k][cc] * sW1[cc*64 + j];
        h1s[k][j] = gelu_f(acc);
    }
    __syncthreads();

    {
        int j = tid & 127, kh = tid >> 7;
        float lmax = -3.402823466e+38f, lsum = 0.f;
        for (int kk = 0; kk < 8; ++kk){
            int k = kh*8 + kk;
            float acc = b2[j];
#pragma unroll 8
            for (int i = 0; i < 64; ++i) acc += h1s[k][i] * sW2[i*128 + j];
            float v = gelu_f(acc);
            lmax = fmaxf(lmax, v);
            lsum += v;
        }
        pmax[kh][j] = lmax; psum[kh][j] = lsum;
    }
    __syncthreads();
    if (tid < 128){
        float mx = pmax[0][tid], sm = psum[0][tid];
#pragma unroll
        for (int w = 1; w < 8; ++w){ mx = fmaxf(mx, pmax[w][tid]); sm += psum[w][tid]; }
        z[tid]       = mx;
        z[128 + tid] = sm * (1.0f/64.0f);
    }
    if (tid >= 128 && tid < 192){   // r stats on wave 2
        int l = tid - 128;
        float r = feat[l][2];
        float s = r, mx = r, mn = r;
        for (int off = 1; off < 64; off <<= 1){
            s  += __shfl_xor(s, off, 64);
            mx  = fmaxf(mx, __shfl_xor(mx, off, 64));
            mn  = fminf(mn, __shfl_xor(mn, off, 64));
        }
        float mean = s * (1.0f/64.0f);
        float dv = (r-mean)*(r-mean);
        for (int off = 1; off < 64; off <<= 1) dv += __shfl_xor(dv, off, 64);
        if (l == 0){
            z[256]=mean; z[257]=mx; z[258]=mn; z[259]=sqrtf(dv*(1.0f/63.0f));
        }
    }
    __syncthreads();

    {
        int j = tid & 127, seg = tid >> 7;
        int i0  = (seg < 4) ? seg*33 : 132 + (seg-4)*32;
        int cntn = (seg < 4) ? 33 : 32;
        float acc = 0.f;
        for (int i = i0; i < i0 + cntn; ++i) acc += z[i]*W3[i*128+j];
        part[seg][j] = acc;
    }
    __syncthreads();
    if (tid < 128){
        float a = part[0][tid];
#pragma unroll
        for (int w = 1; w < 8; ++w) a += part[w][tid];
        zz[tid] = gelu_f(a + b3[tid]);
    }
    __syncthreads();
    {
        int j = tid & 127, seg = tid >> 7;
        float acc = 0.f;
#pragma unroll
        for (int i = seg*16; i < seg*16+16; ++i) acc += zz[i]*W4[i*128+j];
        part[seg][j] = acc;
    }
    __syncthreads();
    if (tid < 128){
        float a = part[0][tid];
#pragma unroll
        for (int w = 1; w < 8; ++w) a += part[w][tid];
        outF[m*128 + tid] = a + b4[tid];
    }
}

extern "C" void kernel_launch(void* const* d_in, const int* in_sizes, int n_in,
                              void* d_out, int out_size, void* d_ws, size_t ws_size,
                              hipStream_t stream)
{
    const float* P  = (const float*)d_in[0];
    const float* W1 = (const float*)d_in[1];
    const float* b1 = (const float*)d_in[2];
    const float* W2 = (const float*)d_in[3];
    const float* b2 = (const float*)d_in[4];
    const float* W3 = (const float*)d_in[5];
    const float* b3 = (const float*)d_in[6];
    const float* W4 = (const float*)d_in[7];
    const float* b4 = (const float*)d_in[8];
    int N = in_sizes[0] / 2;
    float* outF = (float*)d_out;               // [16][128]
    float* outC = outF + MCENT*128;            // [16][2]
    (void)n_in; (void)out_size; (void)ws_size;

    char* base = (char*)d_ws;
    size_t off = 0;
    auto take = [&](size_t bytes)->char*{
        char* p = base + off;
        off = (off + bytes + 255) & ~(size_t)255;
        return p;
    };
    unsigned long long* partials = (unsigned long long*)take((size_t)(MCENT-1)*FPSB*8);
    unsigned int* bcast = (unsigned int*)take(MCENT*4);
    float* cxy         = (float*)take(MCENT*2*4);
    unsigned int* ghist= (unsigned int*)take(MCENT*NBINS*4);
    unsigned int* rhist= (unsigned int*)take(MCENT*RBINS*4);
    unsigned int* cnt  = (unsigned int*)take(MCENT*4);
    float* sc2         = (float*)take(MCENT*4);
    int*   B2          = (int*)  take(MCENT*4);
    float* cd2         = (float*)take((size_t)MCENT*CAP*4);
    int*   cidx        = (int*)  take((size_t)MCENT*CAP*4);

    init_kernel<<<32, 256, 0, stream>>>(ghist, cnt, partials, bcast);

    void* fargs[] = { (void*)&P, (void*)&N, (void*)&partials, (void*)&bcast,
                      (void*)&cxy, (void*)&outC };
    hipLaunchCooperativeKernel((const void*)fps_coop, dim3(FPSB), dim3(FPST),
                               fargs, 0, stream);

    hist_kernel<<<128, 256, 0, stream>>>(P, N, cxy, ghist, rhist);
    thr_kernel<<<1, 64, 0, stream>>>(ghist, sc2);
    refine_kernel<<<1024, 256, 0, stream>>>(P, N, cxy, sc2, rhist);
    thr2_kernel<<<1, 64, 0, stream>>>(rhist, B2);
    collect_kernel<<<1024, 256, 0, stream>>>(P, N, cxy, sc2, B2, cnt, cd2, cidx);
    mlp_kernel<<<MCENT, MLPT, 0, stream>>>(P, cxy, cnt, cd2, cidx,
                                           W1,b1,W2,b2,W3,b3,W4,b4, outF);
}